// Round 15
// baseline (267.817 us; speedup 1.0000x reference)
//
#include <hip/hip_runtime.h>
#include <hip/hip_bf16.h>

// ---------------------------------------------------------------------------
// SpatialInteraction: per-batch channel self-attention
//   S = X X^T  (c=1024, n=4096), attn = softmax_rows(S), out = attn X
// Pipeline: cvt_f4 -> MX-fp4 bt-GEMM (S bf16) -> softmax (+row mask) ->
//           mask-skipping GEMM2 with direct-fp32 B loads (R14-proven).
// R15 gemm_f4: 128x128 tile, 64 KiB LDS -> 2 blocks/CU (first clean test of
// occupancy WITH the R5-proven checkpoint schedule; R9/R10 were confounded).
// Halves = 64 rows = 1 stage instr -> vmcnt counts re-derived: prologue 1,
// CP_mid 3, CP_end 1, peel 0. Same chunk^(row&7) swizzle (8 chunks/row).
// ---------------------------------------------------------------------------

typedef float  f32x4  __attribute__((ext_vector_type(4)));
typedef __bf16 bf16x8 __attribute__((ext_vector_type(8)));
typedef short  s16x8  __attribute__((ext_vector_type(8)));
typedef int    i32x4v __attribute__((ext_vector_type(4)));
typedef int    i32x8v __attribute__((ext_vector_type(8)));

#define BATCH 16
#define C_DIM 1024
#define N_DIM 4096

#define VMW(N) asm volatile("s_waitcnt vmcnt(" #N ")" ::: "memory")
#define SBAR do { asm volatile("" ::: "memory"); __builtin_amdgcn_s_barrier(); \
                  asm volatile("" ::: "memory"); } while (0)

__device__ __forceinline__ unsigned short f2bf(float f) {
  unsigned u = __float_as_uint(f);
  u += 0x7fffu + ((u >> 16) & 1u);        // round-to-nearest-even
  return (unsigned short)(u >> 16);
}

__device__ __forceinline__ float bf2f(unsigned short u) {
  return __uint_as_float((unsigned)u << 16);
}

// fp32 -> OCP e2m1 (fp4). Levels 0,0.5,1,1.5,2,3,4,6; RTNE midpoints.
__device__ __forceinline__ unsigned f2e2m1(float f) {
  const float a = fabsf(f);
  const unsigned s = (__float_as_uint(f) >> 28) & 0x8u;   // sign -> bit 3
  unsigned idx = 0;
  idx += (a >= 0.25f); idx += (a >= 0.75f); idx += (a >= 1.25f);
  idx += (a >= 1.75f); idx += (a >= 2.5f);  idx += (a >= 3.5f);
  idx += (a >= 5.0f);
  return s | idx;
}

__device__ __forceinline__ void gld_lds16(const void* g, void* l) {
  __builtin_amdgcn_global_load_lds(
      (const __attribute__((address_space(1))) unsigned int*)g,
      (__attribute__((address_space(3))) unsigned int*)l, 16, 0, 0);
}

__device__ __forceinline__ i32x8v z8(i32x4v lo) {
  i32x8v v;
  v[0] = lo[0]; v[1] = lo[1]; v[2] = lo[2]; v[3] = lo[3];
  v[4] = 0; v[5] = 0; v[6] = 0; v[7] = 0;   // fp4 uses low 4 regs only
  return v;
}

// ---------------------------------------------------------------------------
// Kernel 0: fp32 -> fp4 grid-stride convert (2 elems/byte, LE nibbles).
// ---------------------------------------------------------------------------
__global__ __launch_bounds__(256) void cvt_f4(const float* __restrict__ x,
                                              unsigned char* __restrict__ xf4,
                                              long n4) {
  size_t i = (size_t)blockIdx.x * 256 + threadIdx.x;
  const size_t stride = (size_t)gridDim.x * 256;
  for (; i < (size_t)n4; i += stride) {
    const float4 v = ((const float4*)x)[i];
    uchar2 q;
    q.x = (unsigned char)(f2e2m1(v.x) | (f2e2m1(v.y) << 4));
    q.y = (unsigned char)(f2e2m1(v.z) | (f2e2m1(v.w) << 4));
    ((uchar2*)xf4)[i] = q;
  }
}

// ---------------------------------------------------------------------------
// Kernel 1: S = Xf4 * Xf4^T per batch, bf16 output. 128x128 tile, 2 blocks/CU.
// LDS: 2 bufs x (A 16K + B 16K) = 64 KiB. K-tile = 256 fp4 = 128 B/row,
// 8 x 16B chunks/row, swizzle chunk' = chunk ^ (row & 7) (proven geometry).
// 8 waves, wave output = 128 rows x 16 cols (acc 8 x f32x4 = 32 VGPR).
// Checkpoint schedule (R5-proven), 1 stage-instr halves: CP_mid vmcnt(3),
// CP_end vmcnt(1). Grid = 8 * 8 * BATCH = 1024 blocks, 512 threads.
// ---------------------------------------------------------------------------
__global__ __launch_bounds__(512, 4)
void gemm_f4_128(const unsigned char* __restrict__ A,
                 unsigned short* __restrict__ C,
                 int ld, long sA, long sC, int gx) {
  __shared__ __align__(16) unsigned char smem[65536];
  // buf b: A at b*32768, B at b*32768 + 16384. Halves at +H*8192.

  const int nwg  = gridDim.x;
  const int orig = blockIdx.x;
  const int wg   = (orig & 7) * (nwg >> 3) + (orig >> 3);
  const int by   = wg & 7;                 // M tile (8)
  const int bx   = (wg >> 3) % gx;         // N tile (8)
  const int bz   = wg / (gx * 8);

  const int tid  = threadIdx.x;
  const int lane = tid & 63;
  const int wc   = tid >> 6;               // 0..7: cols wc*16..+16
  const int r    = lane & 15;
  const int kg   = lane >> 4;              // 0..3

  const unsigned char* Ab = A + (size_t)bz * sA + (size_t)by * 128 * ld;
  const unsigned char* Bb = A + (size_t)bz * sA + (size_t)bx * 128 * ld;

  // staging: half = 64 rows x 8 chunks = 512 chunks = 1 chunk/thread
  const int srow = tid >> 3;               // 0..63 within half
  const int sc   = tid & 7;
  const int ssw  = (sc ^ (srow & 7)) * 16; // swizzled source byte offset

  f32x4 acc[8] = {};                        // 8 i-frags x 1 col-frag
  i32x4v a[4][2], bfrag[2];
  const int NT = 16;                        // 4096 / 256

  // B frag row (= output col) and its LDS addressing
  const int brow = wc * 16 + r;             // 0..127

#define STAGE_H(Gb, H, k0b, bufbase)                                          \
  gld_lds16((Gb) + (size_t)((H) * 64 + srow) * ld + (k0b) + ssw,              \
            smem + (bufbase) + (H) * 8192 + tid * 16)

#define LOADB(bufbase)                                                        \
  do {                                                                        \
    const unsigned char* Bs = smem + (bufbase) + 16384;                       \
    _Pragma("unroll")                                                         \
    for (int kk = 0; kk < 2; ++kk)                                            \
      bfrag[kk] = *(const i32x4v*)(Bs + brow * 128 +                          \
                                   (((kk * 4 + kg) ^ (brow & 7)) * 16));      \
  } while (0)

#define LOADA(bufbase, H)                                                     \
  do {                                                                        \
    const unsigned char* As = smem + (bufbase);                               \
    _Pragma("unroll")                                                         \
    for (int i = 0; i < 4; ++i) {                                             \
      const int row = (H) * 64 + i * 16 + r;                                  \
      _Pragma("unroll")                                                       \
      for (int kk = 0; kk < 2; ++kk)                                          \
        a[i][kk] = *(const i32x4v*)(As + row * 128 +                          \
                                    (((kk * 4 + kg) ^ (row & 7)) * 16));      \
    }                                                                         \
  } while (0)

#define MFMA8(H)                                                              \
  do {                                                                        \
    __builtin_amdgcn_s_setprio(1);                                            \
    _Pragma("unroll")                                                         \
    for (int i = 0; i < 4; ++i)                                               \
      _Pragma("unroll")                                                       \
      for (int kk = 0; kk < 2; ++kk)                                          \
        acc[(H) * 4 + i] = __builtin_amdgcn_mfma_scale_f32_16x16x128_f8f6f4(  \
            z8(a[i][kk]), z8(bfrag[kk]), acc[(H) * 4 + i],                    \
            4, 4, 0, 0x7F7F7F7F, 0, 0x7F7F7F7F);                              \
    __builtin_amdgcn_s_setprio(0);                                            \
  } while (0)

  // ---- prologue: tile 0 -> buf 0, order A0,B0,B1,A1 (1 instr each) ----
  STAGE_H(Ab, 0, 0, 0);
  STAGE_H(Bb, 0, 0, 16384 - 16384 + 16384);  // B half0  (base 0, B offset)
  STAGE_H(Bb, 1, 0, 16384);
  STAGE_H(Ab, 1, 0, 0);
  VMW(1); SBAR;   // A0,B0,B1 landed; A1 in flight

  for (int t = 0; t < NT - 1; ++t) {
    const int cur = (t & 1) * 32768;
    const int nxt = ((t + 1) & 1) * 32768;
    const int k1b = (t + 1) * 128;

    // seg1: stage {A0',B0',B1'}; B frag + A half0; 8 MFMA
    STAGE_H(Ab, 0, k1b, nxt);
    STAGE_H(Bb, 0, k1b, nxt + 16384 - 16384 + 16384);
    STAGE_H(Bb, 1, k1b, nxt + 16384);
    LOADB(cur);
    LOADA(cur, 0);
    MFMA8(0);
    // queue: [A1(t), A0', B0', B1'] -> drain A1(t)
    VMW(3); SBAR;

    // seg2: stage {A1'}; A half1; 8 MFMA
    STAGE_H(Ab, 1, k1b, nxt);
    LOADA(cur, 1);
    MFMA8(1);
    // queue: [A0',B0',B1',A1'] -> drain A0',B0',B1'
    VMW(1); SBAR;
  }

  // ---- peeled last tile ----
  {
    const int cur = ((NT - 1) & 1) * 32768;
    LOADB(cur);
    LOADA(cur, 0);
    MFMA8(0);
    VMW(0); SBAR;               // A1 of last tile landed
    LOADA(cur, 1);
    MFMA8(1);
  }

#undef STAGE_H
#undef LOADB
#undef LOADA
#undef MFMA8

  // ---- epilogue: LDS transpose -> coalesced bf16 stores ----
  // acc[i] holds rows i*16 + kg*4 + jj, col = wc*16 + r of the 128x128 tile.
  unsigned short* Cb = C + (size_t)bz * sC;
  const int rb = by * 128;
  const int cb = bx * 128;
  float* lf = (float*)smem;                 // 64 x 132 f32 = 33.8 KB
  __syncthreads();
#pragma unroll
  for (int q = 0; q < 2; ++q) {             // 2 quarters of 64 rows
#pragma unroll
    for (int i = 0; i < 4; ++i) {
      const int lrow = i * 16 + kg * 4;
      const int col  = wc * 16 + r;
      const f32x4 v = acc[q * 4 + i];
#pragma unroll
      for (int j = 0; j < 4; ++j)
        lf[(lrow + j) * 132 + col] = v[j];
    }
    __syncthreads();
#pragma unroll
    for (int ii = 0; ii < 4; ++ii) {
      const int chunk = ii * 512 + tid;     // 0..2047
      const int row   = chunk >> 5;         // 0..63
      const int cp    = (chunk & 31) * 4;   // 0..124
      const f32x4 v = *(const f32x4*)&lf[row * 132 + cp];
      ushort4 w;
      w.x = f2bf(v[0]); w.y = f2bf(v[1]); w.z = f2bf(v[2]); w.w = f2bf(v[3]);
      *(ushort4*)&Cb[(size_t)(rb + q * 64 + row) * C_DIM + cb + cp] = w;
    }
    __syncthreads();
  }
}

// ---------------------------------------------------------------------------
// Kernel 2: row softmax, S (bf16) -> attn (bf16) + per-row nonzero mask.
// ---------------------------------------------------------------------------
__global__ __launch_bounds__(256) void softmax_rows(const unsigned short* __restrict__ S,
                                                    unsigned short* __restrict__ P,
                                                    unsigned short* __restrict__ rowmask) {
  __shared__ float redm[4];
  __shared__ float reds[4];
  __shared__ unsigned gmask;
  const int t = threadIdx.x;
  const int wid = t >> 6, lane = t & 63;
  const size_t row = blockIdx.x;

  if (t == 0) gmask = 0;
  const ushort4 uv = ((const ushort4*)(S + row * 1024))[t];
  const float vx = bf2f(uv.x), vy = bf2f(uv.y), vz = bf2f(uv.z), vw = bf2f(uv.w);

  float m = fmaxf(fmaxf(vx, vy), fmaxf(vz, vw));
#pragma unroll
  for (int o = 32; o >= 1; o >>= 1) m = fmaxf(m, __shfl_xor(m, o));
  if (lane == 0) redm[wid] = m;
  __syncthreads();
  m = fmaxf(fmaxf(redm[0], redm[1]), fmaxf(redm[2], redm[3]));

  const float e0 = expf(vx - m), e1 = expf(vy - m);
  const float e2 = expf(vz - m), e3 = expf(vw - m);
  float s = (e0 + e1) + (e2 + e3);
#pragma unroll
  for (int o = 32; o >= 1; o >>= 1) s += __shfl_xor(s, o);
  if (lane == 0) reds[wid] = s;
  __syncthreads();
  s = (reds[0] + reds[1]) + (reds[2] + reds[3]);

  const float inv = 1.0f / s;
  ushort4 u;
  u.x = f2bf(e0 * inv); u.y = f2bf(e1 * inv);
  u.z = f2bf(e2 * inv); u.w = f2bf(e3 * inv);
  ((ushort4*)(P + row * 1024))[t] = u;

  const unsigned long long bal = __ballot((u.x | u.y | u.z | u.w) != 0);
  unsigned bits = 0;
#pragma unroll
  for (int q = 0; q < 4; ++q)
    if ((bal >> (16 * q)) & 0xFFFFull) bits |= 1u << (4 * wid + q);
  if (lane == 0) atomicOr(&gmask, bits);
  __syncthreads();
  if (t == 0) rowmask[row] = (unsigned short)gmask;
}

// ---------------------------------------------------------------------------
// Kernel 3: mask-skipping GEMM2 (R14-proven). out[c][n] = sum_d attn[c][d]
// x[d][n]; A staged via gld_lds, B-fragments loaded directly from fp32 x.
// ---------------------------------------------------------------------------
__global__ __launch_bounds__(512, 4)
void gemm_bt_masked(const unsigned short* __restrict__ A,
                    const float* __restrict__ X,
                    float* __restrict__ C,
                    const unsigned short* __restrict__ rowmask,
                    int K, int lda, int ldc,
                    long sA, long sC, int gx) {
  __shared__ unsigned short As[128 * 64];   // 16 KiB
  __shared__ unsigned bmask_sh;

  const int nwg  = gridDim.x;
  const int orig = blockIdx.x;
  const int wg   = (orig & 7) * (nwg >> 3) + (orig >> 3);
  const int by   = wg & 7;
  const int bx   = (wg >> 3) % gx;
  const int bz   = wg / (gx * 8);

  const int tid  = threadIdx.x;
  const int lane = tid & 63;
  const int wid  = tid >> 6;
  const int wr   = wid >> 2;      // 0..1  (M: 2 x 64)
  const int wc   = wid & 3;       // 0..3  (N: 4 x 64)
  const int r    = lane & 15;
  const int kg   = lane >> 4;     // 0..3

  const unsigned short* Ab = A + (size_t)bz * sA + (size_t)by * 128 * lda;
  const float* Xb = X + (size_t)bz * C_DIM * N_DIM;   // x[d][n] fp32

  int ncol[4];
#pragma unroll
  for (int j = 0; j < 4; ++j) ncol[j] = bx * 256 + wc * 64 + j * 16 + r;

  unsigned mym = 0;
  if (tid < 128)
    mym = rowmask[(size_t)bz * C_DIM + by * 128 + tid];
#pragma unroll
  for (int o = 32; o >= 1; o >>= 1) mym |= __shfl_xor(mym, o);
  if (tid == 0) bmask_sh = 0;
  __syncthreads();
  if (tid < 128 && lane == 0) atomicOr(&bmask_sh, mym);
  __syncthreads();
  const unsigned bmask = bmask_sh;

  f32x4 acc[4][4] = {};
  const int NT = K / 64;

#define STAGE_A(k0)                                                           \
  do {                                                                        \
    _Pragma("unroll")                                                         \
    for (int i = 0; i < 2; ++i) {                                             \
      const int ch = i * 512 + tid, row = ch >> 3, c = ch & 7;                \
      gld_lds16(Ab + (size_t)row * lda + (k0) + ((c ^ (row & 7)) * 8),        \
                &As[ch * 8]);                                                 \
    }                                                                         \
  } while (0)

#define COMPUTE(tt)                                                           \
  do {                                                                        \
    _Pragma("unroll")                                                         \
    for (int kk = 0; kk < 2; ++kk) {                                          \
      bf16x8 a[4], b[4];                                                      \
      const int db = (tt) * 64 + kk * 32 + kg * 8;                            \
      _Pragma("unroll")                                                       \
      for (int j = 0; j < 4; ++j) {                                           \
        s16x8 tv;                                                             \
        _Pragma("unroll")                                                     \
        for (int e = 0; e < 8; ++e)                                           \
          tv[e] = (short)f2bf(Xb[(size_t)(db + e) * N_DIM + ncol[j]]);        \
        b[j] = __builtin_bit_cast(bf16x8, tv);                                \
      }                                                                       \
      _Pragma("unroll")                                                       \
      for (int i = 0; i < 4; ++i) {                                           \
        const int ar = wr * 64 + i * 16 + r;                                  \
        a[i] = *(const bf16x8*)&As[ar * 64 + (((kk * 4 + kg) ^ (ar & 7)) * 8)];\
      }                                                                       \
      __builtin_amdgcn_s_setprio(1);                                          \
      _Pragma("unroll")                                                       \
      for (int i = 0; i < 4; ++i)                                             \
        _Pragma("unroll")                                                     \
        for (int j = 0; j < 4; ++j)                                           \
          acc[i][j] = __builtin_amdgcn_mfma_f32_16x16x32_bf16(                \
              a[i], b[j], acc[i][j], 0, 0, 0);                                \
      __builtin_amdgcn_s_setprio(0);                                          \
    }                                                                         \
  } while (0)

  for (int t = 0; t < NT; ++t) {
    if (!((bmask >> t) & 1u)) continue;   // all-zero A-tile: exact skip
    STAGE_A(t * 64);
    VMW(0); SBAR;
    COMPUTE(t);
    SBAR;
  }

#undef STAGE_A
#undef COMPUTE

  float* Cb = C + (size_t)bz * sC;
  const int rb = by * 128 + wr * 64;
  const int cb = bx * 256 + wc * 64;
#pragma unroll
  for (int m = 0; m < 4; ++m) {
    const int row = rb + m * 16 + kg * 4;
#pragma unroll
    for (int n = 0; n < 4; ++n) {
      const int col = cb + n * 16 + r;
      const f32x4 v = acc[m][n];
#pragma unroll
      for (int j = 0; j < 4; ++j)
        Cb[(size_t)(row + j) * ldc + col] = v[j];
    }
  }
}

// ---------------------------------------------------------------------------
extern "C" void kernel_launch(void* const* d_in, const int* in_sizes, int n_in,
                              void* d_out, int out_size, void* d_ws, size_t ws_size,
                              hipStream_t stream) {
  const float* x = (const float*)d_in[0];
  float* out = (float*)d_out;

  // ws layout: xf4 (32 MiB) | attn bf16 (32 MiB) | rowmask (32 KB)
  unsigned char*  ws      = (unsigned char*)d_ws;
  unsigned char*  xf4     = ws;
  unsigned short* attn    = (unsigned short*)(ws + (size_t)BATCH * C_DIM * N_DIM / 2);
  unsigned short* rowmask = attn + (size_t)BATCH * C_DIM * C_DIM;
  unsigned short* S = (unsigned short*)out;   // bf16 scores in d_out,
                                              // overwritten by GEMM2 later

  cvt_f4<<<dim3(2048), 256, 0, stream>>>(
      x, xf4, (long)BATCH * C_DIM * N_DIM / 4);

  // S[c][d] = sum_n xf4[c][n] xf4[d][n]  (M=N=1024, K=4096): 1024 blocks
  gemm_f4_128<<<dim3(8 * 8 * BATCH), 512, 0, stream>>>(
      xf4, S, N_DIM / 2,
      (long)C_DIM * (N_DIM / 2), (long)C_DIM * C_DIM, 8);

  softmax_rows<<<dim3(BATCH * C_DIM), 256, 0, stream>>>(S, attn, rowmask);

  // out[c][n] = sum_d attn[c][d] x[d][n]  (M=1024,N=4096,K=1024): 2048 blocks
  gemm_bt_masked<<<dim3((N_DIM / 256) * 8 * BATCH), 512, 0, stream>>>(
      attn, x, out, rowmask, C_DIM, C_DIM, N_DIM,
      (long)C_DIM * C_DIM, (long)C_DIM * N_DIM, N_DIM / 256);
}

// Round 16
// 255.199 us; speedup vs baseline: 1.0494x; 1.0494x over previous
//
#include <hip/hip_runtime.h>
#include <hip/hip_bf16.h>

// ---------------------------------------------------------------------------
// SpatialInteraction: per-batch channel self-attention
//   S = X X^T  (c=1024, n=4096), attn = softmax_rows(S), out = attn X
// Pipeline: cvt_f4 (fp32->fp4 only; no transpose) -> MX-fp4 bt-GEMM (S bf16)
//   -> softmax (+row nonzero mask) -> mask-skipping GEMM2 whose B-fragments
//   are loaded DIRECTLY from fp32 x (in-register f2bf; xbT buffer deleted).
// R16 = R14 verbatim (measured best: 254.77 us). R15's 128^2 2-blocks/CU
// gemm_f4 regressed (268 us) and is reverted; the occupancy/schedule/tile
// design space for this structure is exhausted (R3-R10, R15).
// ---------------------------------------------------------------------------

typedef float  f32x4  __attribute__((ext_vector_type(4)));
typedef __bf16 bf16x8 __attribute__((ext_vector_type(8)));
typedef short  s16x8  __attribute__((ext_vector_type(8)));
typedef int    i32x4v __attribute__((ext_vector_type(4)));
typedef int    i32x8v __attribute__((ext_vector_type(8)));

#define BATCH 16
#define C_DIM 1024
#define N_DIM 4096

#define VMW(N) asm volatile("s_waitcnt vmcnt(" #N ")" ::: "memory")
#define SBAR do { asm volatile("" ::: "memory"); __builtin_amdgcn_s_barrier(); \
                  asm volatile("" ::: "memory"); } while (0)

__device__ __forceinline__ unsigned short f2bf(float f) {
  unsigned u = __float_as_uint(f);
  u += 0x7fffu + ((u >> 16) & 1u);        // round-to-nearest-even
  return (unsigned short)(u >> 16);
}

__device__ __forceinline__ float bf2f(unsigned short u) {
  return __uint_as_float((unsigned)u << 16);
}

// fp32 -> OCP e2m1 (fp4). Levels 0,0.5,1,1.5,2,3,4,6; RTNE midpoints.
__device__ __forceinline__ unsigned f2e2m1(float f) {
  const float a = fabsf(f);
  const unsigned s = (__float_as_uint(f) >> 28) & 0x8u;   // sign -> bit 3
  unsigned idx = 0;
  idx += (a >= 0.25f); idx += (a >= 0.75f); idx += (a >= 1.25f);
  idx += (a >= 1.75f); idx += (a >= 2.5f);  idx += (a >= 3.5f);
  idx += (a >= 5.0f);
  return s | idx;
}

__device__ __forceinline__ void gld_lds16(const void* g, void* l) {
  __builtin_amdgcn_global_load_lds(
      (const __attribute__((address_space(1))) unsigned int*)g,
      (__attribute__((address_space(3))) unsigned int*)l, 16, 0, 0);
}

__device__ __forceinline__ i32x8v z8(i32x4v lo) {
  i32x8v v;
  v[0] = lo[0]; v[1] = lo[1]; v[2] = lo[2]; v[3] = lo[3];
  v[4] = 0; v[5] = 0; v[6] = 0; v[7] = 0;   // fp4 uses low 4 regs only
  return v;
}

// ---------------------------------------------------------------------------
// Kernel 0: fp32 -> fp4 grid-stride convert (2 elems/byte, LE nibbles).
// ---------------------------------------------------------------------------
__global__ __launch_bounds__(256) void cvt_f4(const float* __restrict__ x,
                                              unsigned char* __restrict__ xf4,
                                              long n4) {
  size_t i = (size_t)blockIdx.x * 256 + threadIdx.x;
  const size_t stride = (size_t)gridDim.x * 256;
  for (; i < (size_t)n4; i += stride) {
    const float4 v = ((const float4*)x)[i];
    uchar2 q;
    q.x = (unsigned char)(f2e2m1(v.x) | (f2e2m1(v.y) << 4));
    q.y = (unsigned char)(f2e2m1(v.z) | (f2e2m1(v.w) << 4));
    ((uchar2*)xf4)[i] = q;
  }
}

// ---------------------------------------------------------------------------
// MX-fp4 GEMM1 helpers (R13-proven). Per matrix per buffer: 256 rows x 128 B;
// 8 x 16B chunks/row, swizzle chunk' = chunk ^ (row & 7) on the GLOBAL source
// at stage and on the ds_read address (LDS linear).
// ---------------------------------------------------------------------------

template<int H>
__device__ __forceinline__ void stage_half4(const unsigned char* __restrict__ Gb,
                                            int ld, int k0b,
                                            unsigned char* matbase, int tid) {
  unsigned char* lhalf = matbase + H * 128 * 128;
#pragma unroll
  for (int i = 0; i < 2; ++i) {
    const int chunk = i * 512 + tid;     // 0..1023 within half
    const int row   = chunk >> 3;        // 0..127
    const int c16   = chunk & 7;
    const int grow  = H * 128 + row;
    gld_lds16(Gb + (size_t)grow * ld + k0b + ((c16 ^ (row & 7)) * 16),
              lhalf + chunk * 16);
  }
}

template<int MH>
__device__ __forceinline__ void loadA4(const unsigned char* __restrict__ As,
                                       i32x4v (&a)[4][2], int wr, int r, int kg) {
#pragma unroll
  for (int i = 0; i < 4; ++i) {
    const int row = MH * 128 + wr * 64 + i * 16 + r;
    const int base = row * 128;
#pragma unroll
    for (int kk = 0; kk < 2; ++kk)
      a[i][kk] = *(const i32x4v*)(As + base + (((kk * 4 + kg) ^ (row & 7)) * 16));
  }
}

template<int NH>
__device__ __forceinline__ void loadB4(const unsigned char* __restrict__ Bs,
                                       i32x4v (&b)[2][2], int wc, int r, int kg) {
#pragma unroll
  for (int j = 0; j < 2; ++j) {
    const int row = NH * 128 + wc * 32 + j * 16 + r;
    const int base = row * 128;
#pragma unroll
    for (int kk = 0; kk < 2; ++kk)
      b[j][kk] = *(const i32x4v*)(Bs + base + (((kk * 4 + kg) ^ (row & 7)) * 16));
  }
}

template<int MH, int NH>
__device__ __forceinline__ void quad4(const i32x4v (&a)[4][2],
                                      const i32x4v (&b)[2][2],
                                      f32x4 (&acc)[8][4]) {
  __builtin_amdgcn_s_setprio(1);
#pragma unroll
  for (int i = 0; i < 4; ++i)
#pragma unroll
    for (int j = 0; j < 2; ++j)
#pragma unroll
      for (int kk = 0; kk < 2; ++kk)
        acc[MH * 4 + i][NH * 2 + j] =
            __builtin_amdgcn_mfma_scale_f32_16x16x128_f8f6f4(
                z8(a[i][kk]), z8(b[j][kk]), acc[MH * 4 + i][NH * 2 + j],
                4, 4,                      // cbsz = blgp = fp4 (e2m1)
                0, 0x7F7F7F7F,             // A scales = 1.0 (E8M0 127)
                0, 0x7F7F7F7F);            // B scales = 1.0
  __builtin_amdgcn_s_setprio(0);
}

// ---------------------------------------------------------------------------
// Kernel 1: S = Xf4 * Xf4^T per batch, bf16 output (R13-proven).
// 256x256 tile, K-tile = 256 fp4 = 128 B, checkpoint schedule.
// 1D grid = 4 * 4 * BATCH = 256 blocks, 512 threads.
// ---------------------------------------------------------------------------
__global__ __launch_bounds__(512, 2)
void gemm_f4(const unsigned char* __restrict__ A,
             unsigned short* __restrict__ C,
             int ld, long sA, long sC, int gx) {
  __shared__ __align__(16) unsigned char smem[131072];  // 2 x (A 32K + B 32K)

  const int nwg  = gridDim.x;
  const int orig = blockIdx.x;
  const int wg   = (orig & 7) * (nwg >> 3) + (orig >> 3);
  const int by   = wg & 3;
  const int bx   = (wg >> 2) % gx;
  const int bz   = wg / (gx * 4);

  const int tid  = threadIdx.x;
  const int lane = tid & 63;
  const int wid  = tid >> 6;
  const int wr   = wid >> 2;      // 0..1
  const int wc   = wid & 3;       // 0..3
  const int r    = lane & 15;
  const int kg   = lane >> 4;     // 0..3

  const unsigned char* Ab = A + (size_t)bz * sA + (size_t)by * 256 * ld;
  const unsigned char* Bb = A + (size_t)bz * sA + (size_t)bx * 256 * ld;

  f32x4 acc[8][4] = {};
  i32x4v a[4][2], b0[2][2], b1[2][2];
  const int NT = 16;               // 4096 k-elems / 256 per tile

  {
    unsigned char* A0 = smem;
    unsigned char* B0 = smem + 32768;
    stage_half4<0>(Ab, ld, 0, A0, tid);
    stage_half4<0>(Bb, ld, 0, B0, tid);
    stage_half4<1>(Bb, ld, 0, B0, tid);
    stage_half4<1>(Ab, ld, 0, A0, tid);
  }
  VMW(2); SBAR;   // A0,B0,B1 landed (A1 in flight)

  for (int t = 0; t < NT - 1; ++t) {
    const unsigned char* Ac = smem + (t & 1) * 65536;
    const unsigned char* Bc = Ac + 32768;
    unsigned char* An = smem + ((t + 1) & 1) * 65536;
    unsigned char* Bn = An + 32768;
    const int k1b = (t + 1) * 128;   // 256 fp4 elems = 128 bytes

    stage_half4<0>(Ab, ld, k1b, An, tid);
    stage_half4<0>(Bb, ld, k1b, Bn, tid);
    stage_half4<1>(Bb, ld, k1b, Bn, tid);
    loadA4<0>(Ac, a, wr, r, kg);
    loadB4<0>(Bc, b0, wc, r, kg);
    quad4<0, 0>(a, b0, acc);
    loadB4<1>(Bc, b1, wc, r, kg);
    quad4<0, 1>(a, b1, acc);
    VMW(6); SBAR;   // drain A1(t)

    stage_half4<1>(Ab, ld, k1b, An, tid);
    loadA4<1>(Ac, a, wr, r, kg);
    quad4<1, 0>(a, b0, acc);
    quad4<1, 1>(a, b1, acc);
    VMW(2); SBAR;   // drain A0',B0',B1'
  }

  {
    const unsigned char* Ac = smem + ((NT - 1) & 1) * 65536;
    const unsigned char* Bc = Ac + 32768;
    loadA4<0>(Ac, a, wr, r, kg);
    loadB4<0>(Bc, b0, wc, r, kg);
    quad4<0, 0>(a, b0, acc);
    loadB4<1>(Bc, b1, wc, r, kg);
    quad4<0, 1>(a, b1, acc);
    VMW(0); SBAR;               // A1 of last tile landed
    loadA4<1>(Ac, a, wr, r, kg);
    quad4<1, 0>(a, b0, acc);
    quad4<1, 1>(a, b1, acc);
  }

  // epilogue: LDS transpose -> coalesced bf16 stores
  unsigned short* Cb = C + (size_t)bz * sC;
  const int rb = by * 256;
  const int cb = bx * 256;
  float* lf = (float*)smem;
  __syncthreads();
#pragma unroll
  for (int q = 0; q < 4; ++q) {
    if (wr == (q & 1)) {
      const int MH = q >> 1;
#pragma unroll
      for (int i = 0; i < 4; ++i) {
#pragma unroll
        for (int n = 0; n < 4; ++n) {
          const int col  = (n >> 1) * 128 + wc * 32 + (n & 1) * 16 + r;
          const int lrow = i * 16 + kg * 4;
          const f32x4 v = acc[MH * 4 + i][n];
#pragma unroll
          for (int j = 0; j < 4; ++j)
            lf[(lrow + j) * 260 + col] = v[j];
        }
      }
    }
    __syncthreads();
#pragma unroll
    for (int i = 0; i < 8; ++i) {
      const int chunk = i * 512 + tid;
      const int row   = chunk >> 6;
      const int cp    = (chunk & 63) * 4;
      const f32x4 v = *(const f32x4*)&lf[row * 260 + cp];
      ushort4 w;
      w.x = f2bf(v[0]); w.y = f2bf(v[1]); w.z = f2bf(v[2]); w.w = f2bf(v[3]);
      *(ushort4*)&Cb[(size_t)(rb + q * 64 + row) * C_DIM + cb + cp] = w;
    }
    __syncthreads();
  }
}

// ---------------------------------------------------------------------------
// Kernel 2: row softmax, S (bf16) -> attn (bf16) + per-row nonzero mask.
// ---------------------------------------------------------------------------
__global__ __launch_bounds__(256) void softmax_rows(const unsigned short* __restrict__ S,
                                                    unsigned short* __restrict__ P,
                                                    unsigned short* __restrict__ rowmask) {
  __shared__ float redm[4];
  __shared__ float reds[4];
  __shared__ unsigned gmask;
  const int t = threadIdx.x;
  const int wid = t >> 6, lane = t & 63;
  const size_t row = blockIdx.x;

  if (t == 0) gmask = 0;
  const ushort4 uv = ((const ushort4*)(S + row * 1024))[t];
  const float vx = bf2f(uv.x), vy = bf2f(uv.y), vz = bf2f(uv.z), vw = bf2f(uv.w);

  float m = fmaxf(fmaxf(vx, vy), fmaxf(vz, vw));
#pragma unroll
  for (int o = 32; o >= 1; o >>= 1) m = fmaxf(m, __shfl_xor(m, o));
  if (lane == 0) redm[wid] = m;
  __syncthreads();
  m = fmaxf(fmaxf(redm[0], redm[1]), fmaxf(redm[2], redm[3]));

  const float e0 = expf(vx - m), e1 = expf(vy - m);
  const float e2 = expf(vz - m), e3 = expf(vw - m);
  float s = (e0 + e1) + (e2 + e3);
#pragma unroll
  for (int o = 32; o >= 1; o >>= 1) s += __shfl_xor(s, o);
  if (lane == 0) reds[wid] = s;
  __syncthreads();
  s = (reds[0] + reds[1]) + (reds[2] + reds[3]);

  const float inv = 1.0f / s;
  ushort4 u;
  u.x = f2bf(e0 * inv); u.y = f2bf(e1 * inv);
  u.z = f2bf(e2 * inv); u.w = f2bf(e3 * inv);
  ((ushort4*)(P + row * 1024))[t] = u;

  const unsigned long long bal = __ballot((u.x | u.y | u.z | u.w) != 0);
  unsigned bits = 0;
#pragma unroll
  for (int q = 0; q < 4; ++q)
    if ((bal >> (16 * q)) & 0xFFFFull) bits |= 1u << (4 * wid + q);
  if (lane == 0) atomicOr(&gmask, bits);
  __syncthreads();
  if (t == 0) rowmask[row] = (unsigned short)gmask;
}

// ---------------------------------------------------------------------------
// Kernel 3: mask-skipping GEMM2 (R14-proven). out[c][n] = sum_d attn[c][d]
// x[d][n]; A staged via gld_lds, B-fragments loaded directly from fp32 x.
// 128x256 tile, BK=64, 8 waves, per-wave 64x64 out; skips all-zero A-tiles.
// ---------------------------------------------------------------------------
__global__ __launch_bounds__(512, 4)
void gemm_bt_masked(const unsigned short* __restrict__ A,
                    const float* __restrict__ X,
                    float* __restrict__ C,
                    const unsigned short* __restrict__ rowmask,
                    int K, int lda, int ldc,
                    long sA, long sC, int gx) {
  __shared__ unsigned short As[128 * 64];   // 16 KiB
  __shared__ unsigned bmask_sh;

  const int nwg  = gridDim.x;
  const int orig = blockIdx.x;
  const int wg   = (orig & 7) * (nwg >> 3) + (orig >> 3);
  const int by   = wg & 7;
  const int bx   = (wg >> 3) % gx;
  const int bz   = wg / (gx * 8);

  const int tid  = threadIdx.x;
  const int lane = tid & 63;
  const int wid  = tid >> 6;
  const int wr   = wid >> 2;      // 0..1  (M: 2 x 64)
  const int wc   = wid & 3;       // 0..3  (N: 4 x 64)
  const int r    = lane & 15;
  const int kg   = lane >> 4;     // 0..3

  const unsigned short* Ab = A + (size_t)bz * sA + (size_t)by * 128 * lda;
  const float* Xb = X + (size_t)bz * C_DIM * N_DIM;   // x[d][n] fp32

  int ncol[4];
#pragma unroll
  for (int j = 0; j < 4; ++j) ncol[j] = bx * 256 + wc * 64 + j * 16 + r;

  unsigned mym = 0;
  if (tid < 128)
    mym = rowmask[(size_t)bz * C_DIM + by * 128 + tid];
#pragma unroll
  for (int o = 32; o >= 1; o >>= 1) mym |= __shfl_xor(mym, o);
  if (tid == 0) bmask_sh = 0;
  __syncthreads();
  if (tid < 128 && lane == 0) atomicOr(&bmask_sh, mym);
  __syncthreads();
  const unsigned bmask = bmask_sh;

  f32x4 acc[4][4] = {};
  const int NT = K / 64;

#define STAGE_A(k0)                                                           \
  do {                                                                        \
    _Pragma("unroll")                                                         \
    for (int i = 0; i < 2; ++i) {                                             \
      const int ch = i * 512 + tid, row = ch >> 3, c = ch & 7;                \
      gld_lds16(Ab + (size_t)row * lda + (k0) + ((c ^ (row & 7)) * 8),        \
                &As[ch * 8]);                                                 \
    }                                                                         \
  } while (0)

#define COMPUTE(tt)                                                           \
  do {                                                                        \
    _Pragma("unroll")                                                         \
    for (int kk = 0; kk < 2; ++kk) {                                          \
      bf16x8 a[4], b[4];                                                      \
      const int db = (tt) * 64 + kk * 32 + kg * 8;                            \
      _Pragma("unroll")                                                       \
      for (int j = 0; j < 4; ++j) {                                           \
        s16x8 tv;                                                             \
        _Pragma("unroll")                                                     \
        for (int e = 0; e < 8; ++e)                                           \
          tv[e] = (short)f2bf(Xb[(size_t)(db + e) * N_DIM + ncol[j]]);        \
        b[j] = __builtin_bit_cast(bf16x8, tv);                                \
      }                                                                       \
      _Pragma("unroll")                                                       \
      for (int i = 0; i < 4; ++i) {                                           \
        const int ar = wr * 64 + i * 16 + r;                                  \
        a[i] = *(const bf16x8*)&As[ar * 64 + (((kk * 4 + kg) ^ (ar & 7)) * 8)];\
      }                                                                       \
      __builtin_amdgcn_s_setprio(1);                                          \
      _Pragma("unroll")                                                       \
      for (int i = 0; i < 4; ++i)                                             \
        _Pragma("unroll")                                                     \
        for (int j = 0; j < 4; ++j)                                           \
          acc[i][j] = __builtin_amdgcn_mfma_f32_16x16x32_bf16(                \
              a[i], b[j], acc[i][j], 0, 0, 0);                                \
      __builtin_amdgcn_s_setprio(0);                                          \
    }                                                                         \
  } while (0)

  for (int t = 0; t < NT; ++t) {
    if (!((bmask >> t) & 1u)) continue;   // all-zero A-tile: exact skip
    STAGE_A(t * 64);
    VMW(0); SBAR;
    COMPUTE(t);
    SBAR;
  }

#undef STAGE_A
#undef COMPUTE

  float* Cb = C + (size_t)bz * sC;
  const int rb = by * 128 + wr * 64;
  const int cb = bx * 256 + wc * 64;
#pragma unroll
  for (int m = 0; m < 4; ++m) {
    const int row = rb + m * 16 + kg * 4;
#pragma unroll
    for (int n = 0; n < 4; ++n) {
      const int col = cb + n * 16 + r;
      const f32x4 v = acc[m][n];
#pragma unroll
      for (int j = 0; j < 4; ++j)
        Cb[(size_t)(row + j) * ldc + col] = v[j];
    }
  }
}

// ---------------------------------------------------------------------------
extern "C" void kernel_launch(void* const* d_in, const int* in_sizes, int n_in,
                              void* d_out, int out_size, void* d_ws, size_t ws_size,
                              hipStream_t stream) {
  const float* x = (const float*)d_in[0];
  float* out = (float*)d_out;

  // ws layout: xf4 (32 MiB) | attn bf16 (32 MiB) | rowmask (32 KB)
  unsigned char*  ws      = (unsigned char*)d_ws;
  unsigned char*  xf4     = ws;
  unsigned short* attn    = (unsigned short*)(ws + (size_t)BATCH * C_DIM * N_DIM / 2);
  unsigned short* rowmask = attn + (size_t)BATCH * C_DIM * C_DIM;
  unsigned short* S = (unsigned short*)out;   // bf16 scores in d_out,
                                              // overwritten by GEMM2 later

  cvt_f4<<<dim3(2048), 256, 0, stream>>>(
      x, xf4, (long)BATCH * C_DIM * N_DIM / 4);

  // S[c][d] = sum_n xf4[c][n] xf4[d][n]  (M=N=1024, K=4096): 256 blocks
  gemm_f4<<<dim3((C_DIM / 256) * (C_DIM / 256) * BATCH), 512, 0, stream>>>(
      xf4, S, N_DIM / 2,
      (long)C_DIM * (N_DIM / 2), (long)C_DIM * C_DIM, C_DIM / 256);

  softmax_rows<<<dim3(BATCH * C_DIM), 256, 0, stream>>>(S, attn, rowmask);

  // out[c][n] = sum_d attn[c][d] x[d][n]  (M=1024,N=4096,K=1024): 2048 blocks
  gemm_bt_masked<<<dim3((N_DIM / 256) * 8 * BATCH), 512, 0, stream>>>(
      attn, x, out, rowmask, C_DIM, C_DIM, N_DIM,
      (long)C_DIM * C_DIM, (long)C_DIM * N_DIM, N_DIM / 256);
}